// Round 1
// baseline (199.854 us; speedup 1.0000x reference)
//
#include <hip/hip_runtime.h>
#include <hip/hip_fp16.h>

typedef _Float16 f16;
typedef _Float16 f16x8 __attribute__((ext_vector_type(8)));
typedef _Float16 f16x4v __attribute__((ext_vector_type(4)));
typedef float f32x4 __attribute__((ext_vector_type(4)));

#define B_ 2
#define S_ 2048
#define E_ 1024
#define H_ 16
#define DH_ 64

__device__ __forceinline__ f32x4 mfma16(f16x8 a, f16x8 b, f32x4 c) {
    return __builtin_amdgcn_mfma_f32_16x16x32_f16(a, b, c, 0, 0, 0);
}

__device__ __forceinline__ f16x8 cvt8(const float* p) {
    float4 v0 = *(const float4*)p;
    float4 v1 = *(const float4*)(p + 4);
    f16x8 r;
    r[0] = (f16)v0.x; r[1] = (f16)v0.y; r[2] = (f16)v0.z; r[3] = (f16)v0.w;
    r[4] = (f16)v1.x; r[5] = (f16)v1.y; r[6] = (f16)v1.z; r[7] = (f16)v1.w;
    return r;
}

// ---------------------------------------------------------------------------
// Kernel 1: per-head projections. One wave = 16 s-rows of one (b,h) for one of
// {Q,K,V}. A = x rows (16x64 fp32 -> f16), B-op = W rows (e,d). 8 MFMAs/wave.
// Q,K out: [bh][s][d].  V out transposed: Vt[bh][d][s] (acc j-values are
// s-consecutive -> packed 8B stores).
// ---------------------------------------------------------------------------
__global__ __launch_bounds__(256) void proj_kernel(
    const float* __restrict__ q_in, const float* __restrict__ k_in,
    const float* __restrict__ v_in,
    const float* __restrict__ Wq, const float* __restrict__ Wk,
    const float* __restrict__ Wv,
    f16* __restrict__ Qg, f16* __restrict__ Kg, f16* __restrict__ Vt)
{
    int tid = threadIdx.x;
    int lane = tid & 63, wv = tid >> 6;
    int wid = blockIdx.x * 4 + wv;        // 0..12287
    int proj = wid >> 12;                 // 0:Q 1:K 2:V
    int r = wid & 4095;
    int bh = r >> 7;                      // 0..31
    int stile = r & 127;
    int sbase = stile * 16;
    int h = bh & 15;
    int b = bh >> 4;
    int c = lane & 15, g = lane >> 4;

    const float* x; const float* W;
    if (proj == 0)      { x = q_in; W = Wq; }
    else if (proj == 1) { x = k_in; W = Wk; }
    else                { x = v_in; W = Wv; }

    // A-frags: row s = sbase + c, k = d
    const float* xrow = x + (((size_t)(b * S_ + sbase + c) * H_ + h) << 6);
    f16x8 a0 = cvt8(xrow + g * 8);
    f16x8 a1 = cvt8(xrow + 32 + g * 8);

    f32x4 acc[4] = {};
#pragma unroll
    for (int nt = 0; nt < 4; ++nt) {
        const float* wrow = W + ((nt * 16 + c) << 6);
        f16x8 b0 = cvt8(wrow + g * 8);
        f16x8 b1 = cvt8(wrow + 32 + g * 8);
        acc[nt] = mfma16(a0, b0, acc[nt]);
        acc[nt] = mfma16(a1, b1, acc[nt]);
    }

    if (proj < 2) {
        f16* out = (proj == 0) ? Qg : Kg;
#pragma unroll
        for (int nt = 0; nt < 4; ++nt)
#pragma unroll
            for (int j = 0; j < 4; ++j) {
                int s = sbase + g * 4 + j;
                out[((size_t)bh * S_ + s) * DH_ + nt * 16 + c] = (f16)acc[nt][j];
            }
    } else {
#pragma unroll
        for (int nt = 0; nt < 4; ++nt) {
            f16x4v pk;
            pk[0] = (f16)acc[nt][0]; pk[1] = (f16)acc[nt][1];
            pk[2] = (f16)acc[nt][2]; pk[3] = (f16)acc[nt][3];
            *(f16x4v*)&Vt[((size_t)bh * DH_ + nt * 16 + c) * S_ + sbase + g * 4] = pk;
        }
    }
}

// ---------------------------------------------------------------------------
// Kernel 2: Wo fp32 -> fp16
// ---------------------------------------------------------------------------
__global__ __launch_bounds__(256) void cvt_wo(const float* __restrict__ W,
                                              f16* __restrict__ out)
{
    int i = blockIdx.x * 256 + threadIdx.x;   // 1M/4 = 262144 threads
    float4 v = *(const float4*)(W + (size_t)i * 4);
    f16x4v o;
    o[0] = (f16)v.x; o[1] = (f16)v.y; o[2] = (f16)v.z; o[3] = (f16)v.w;
    *(f16x4v*)(out + (size_t)i * 4) = o;
}

// ---------------------------------------------------------------------------
// Kernel 3: flash attention. Block = 4 waves, each wave owns 16 q-rows of one
// (b,h). 64-key tiles: K tile + Vt tile staged in padded LDS. Online softmax.
// P goes through a padded fp32 LDS slab (per-wave) to become PV's A-fragment.
// ---------------------------------------------------------------------------
__global__ __launch_bounds__(256) void attn_kernel(
    const f16* __restrict__ Qg, const f16* __restrict__ Kg,
    const f16* __restrict__ Vt, f16* __restrict__ ctx)
{
    __shared__ __align__(16) f16 Klds[64][72];    // [key][d] +8 pad
    __shared__ __align__(16) f16 Vtlds[64][72];   // [d][key] +8 pad
    __shared__ __align__(16) float Plds[4][16][68]; // per-wave [q][key] fp32

    int tid = threadIdx.x, lane = tid & 63, wv = tid >> 6;
    int bx = blockIdx.x;
    int bh = bx >> 5, qt = bx & 31;
    int b = bh >> 4, h = bh & 15;
    int qbase = qt * 64 + wv * 16;
    int c = lane & 15, g = lane >> 4;

    const f16* Qh = Qg + (size_t)bh * S_ * DH_;
    const f16* Kh = Kg + (size_t)bh * S_ * DH_;
    const f16* Vh = Vt + (size_t)bh * DH_ * S_;

    f16x8 aq0 = *(const f16x8*)(Qh + (qbase + c) * DH_ + g * 8);
    f16x8 aq1 = *(const f16x8*)(Qh + (qbase + c) * DH_ + 32 + g * 8);

    float m_run[4], l_run[4];
    f32x4 accO[4] = {};
#pragma unroll
    for (int j = 0; j < 4; ++j) { m_run[j] = -1e30f; l_run[j] = 0.f; }

#pragma unroll 1
    for (int kt = 0; kt < 32; ++kt) {
        int kbase = kt * 64;
        __syncthreads();
        // stage K tile [64 keys][64 d] and Vt tile [64 d][64 keys]
#pragma unroll
        for (int i = 0; i < 2; ++i) {
            int idx = i * 256 + tid;        // 0..511
            int row = idx >> 3, cc = idx & 7;
            *(f16x8*)&Klds[row][cc * 8] =
                *(const f16x8*)(Kh + (size_t)(kbase + row) * DH_ + cc * 8);
            *(f16x8*)&Vtlds[row][cc * 8] =
                *(const f16x8*)(Vh + (size_t)row * S_ + kbase + cc * 8);
        }
        __syncthreads();

        // QK^T: acc col = key (lane&15), row = q (g*4+j)
        f32x4 accS[4] = {};
#pragma unroll
        for (int sub = 0; sub < 4; ++sub) {
            f16x8 b0 = *(const f16x8*)&Klds[sub * 16 + c][g * 8];
            f16x8 b1 = *(const f16x8*)&Klds[sub * 16 + c][32 + g * 8];
            accS[sub] = mfma16(aq0, b0, accS[sub]);
            accS[sub] = mfma16(aq1, b1, accS[sub]);
        }

        // online softmax (per q-row j; 16-lane butterfly over key lanes)
        float p[4][4];
        float alpha[4];
#pragma unroll
        for (int j = 0; j < 4; ++j) {
            float mx = fmaxf(fmaxf(accS[0][j], accS[1][j]),
                             fmaxf(accS[2][j], accS[3][j])) * 0.125f;
#pragma unroll
            for (int d = 1; d < 16; d <<= 1) mx = fmaxf(mx, __shfl_xor(mx, d));
            float mn = fmaxf(m_run[j], mx);
            alpha[j] = __expf(m_run[j] - mn);
            m_run[j] = mn;
            float rs = 0.f;
#pragma unroll
            for (int sub = 0; sub < 4; ++sub) {
                float pv = __expf(accS[sub][j] * 0.125f - mn);
                p[sub][j] = pv; rs += pv;
            }
#pragma unroll
            for (int d = 1; d < 16; d <<= 1) rs += __shfl_xor(rs, d);
            l_run[j] = l_run[j] * alpha[j] + rs;
        }
#pragma unroll
        for (int nt = 0; nt < 4; ++nt)
#pragma unroll
            for (int j = 0; j < 4; ++j) accO[nt][j] *= alpha[j];

        // transpose P via per-wave LDS slab
#pragma unroll
        for (int sub = 0; sub < 4; ++sub)
#pragma unroll
            for (int j = 0; j < 4; ++j)
                Plds[wv][g * 4 + j][sub * 16 + c] = p[sub][j];
        __syncthreads();

        // PV: A = P (q x keys), B-op = Vt rows (d, keys)
#pragma unroll
        for (int ch = 0; ch < 2; ++ch) {
            const float* prow = &Plds[wv][c][ch * 32 + g * 8];
            float4 p0 = *(const float4*)prow;
            float4 p1 = *(const float4*)(prow + 4);
            f16x8 pa;
            pa[0] = (f16)p0.x; pa[1] = (f16)p0.y; pa[2] = (f16)p0.z; pa[3] = (f16)p0.w;
            pa[4] = (f16)p1.x; pa[5] = (f16)p1.y; pa[6] = (f16)p1.z; pa[7] = (f16)p1.w;
#pragma unroll
            for (int nt = 0; nt < 4; ++nt) {
                f16x8 bv = *(const f16x8*)&Vtlds[nt * 16 + c][ch * 32 + g * 8];
                accO[nt] = mfma16(pa, bv, accO[nt]);
            }
        }
    }

    // epilogue: divide by l, write ctx[b][s][h*64+d] (concat layout, f16)
    float inv[4];
#pragma unroll
    for (int j = 0; j < 4; ++j) inv[j] = 1.f / l_run[j];
#pragma unroll
    for (int nt = 0; nt < 4; ++nt)
#pragma unroll
        for (int j = 0; j < 4; ++j) {
            int s = qbase + g * 4 + j;
            ctx[((size_t)b * S_ + s) * E_ + h * DH_ + nt * 16 + c] =
                (f16)(accO[nt][j] * inv[j]);
        }
}

// ---------------------------------------------------------------------------
// Kernel 4: out = ctx @ Wo^T + bo.  M=4096, N=1024, K=1024. 128x128 tile,
// BK=32, 4 waves each 64x64. Reg-staged LDS (single-buffered).
// ---------------------------------------------------------------------------
__global__ __launch_bounds__(256) void gemm_out(
    const f16* __restrict__ A,    // ctx [4096][1024]
    const f16* __restrict__ Bw,   // Wo f16 [1024][1024] (rows = e, cols = k)
    const float* __restrict__ bo,
    float* __restrict__ out)      // [4096][1024] fp32
{
    __shared__ __align__(16) f16 Al[128][32];
    __shared__ __align__(16) f16 Bl[128][32];

    int tid = threadIdx.x, lane = tid & 63, wv = tid >> 6;
    int mbase = blockIdx.x * 128, nbase = blockIdx.y * 128;
    int c = lane & 15, g = lane >> 4;
    int wr = wv >> 1, wc = wv & 1;

    f32x4 acc[4][4] = {};

#pragma unroll 1
    for (int kb = 0; kb < 1024; kb += 32) {
        __syncthreads();
#pragma unroll
        for (int i = 0; i < 2; ++i) {
            int idx = i * 256 + tid;     // 0..511
            int row = idx >> 2, chunk = idx & 3;
            *(f16x8*)&Al[row][chunk * 8] =
                *(const f16x8*)(A + (size_t)(mbase + row) * 1024 + kb + chunk * 8);
            *(f16x8*)&Bl[row][chunk * 8] =
                *(const f16x8*)(Bw + (size_t)(nbase + row) * 1024 + kb + chunk * 8);
        }
        __syncthreads();

        f16x8 af[4], bf[4];
#pragma unroll
        for (int mi = 0; mi < 4; ++mi)
            af[mi] = *(const f16x8*)&Al[wr * 64 + mi * 16 + c][g * 8];
#pragma unroll
        for (int ni = 0; ni < 4; ++ni)
            bf[ni] = *(const f16x8*)&Bl[wc * 64 + ni * 16 + c][g * 8];
#pragma unroll
        for (int mi = 0; mi < 4; ++mi)
#pragma unroll
            for (int ni = 0; ni < 4; ++ni)
                acc[mi][ni] = mfma16(af[mi], bf[ni], acc[mi][ni]);
    }

    // epilogue: + bias, fp32 store
#pragma unroll
    for (int ni = 0; ni < 4; ++ni) {
        float bias = bo[nbase + wc * 64 + ni * 16 + c];
#pragma unroll
        for (int mi = 0; mi < 4; ++mi)
#pragma unroll
            for (int j = 0; j < 4; ++j) {
                int m = mbase + wr * 64 + mi * 16 + g * 4 + j;
                out[(size_t)m * 1024 + nbase + wc * 64 + ni * 16 + c] =
                    acc[mi][ni][j] + bias;
            }
    }
}

extern "C" void kernel_launch(void* const* d_in, const int* in_sizes, int n_in,
                              void* d_out, int out_size, void* d_ws, size_t ws_size,
                              hipStream_t stream)
{
    const float* k_in = (const float*)d_in[0];
    const float* q_in = (const float*)d_in[1];
    const float* v_in = (const float*)d_in[2];
    const float* Wq   = (const float*)d_in[3];
    const float* Wk   = (const float*)d_in[4];
    const float* Wv   = (const float*)d_in[5];
    const float* Wo   = (const float*)d_in[6];
    const float* bo   = (const float*)d_in[7];
    float* out = (float*)d_out;

    char* ws = (char*)d_ws;
    f16* Qg  = (f16*)(ws);                       // 8 MB
    f16* Kg  = (f16*)(ws + (8u << 20));          // 8 MB
    f16* Vt  = (f16*)(ws + (16u << 20));         // 8 MB
    f16* ctx = (f16*)(ws + (24u << 20));         // 8 MB
    f16* WoH = (f16*)(ws + (32u << 20));         // 2 MB

    proj_kernel<<<dim3(3072), dim3(256), 0, stream>>>(q_in, k_in, v_in,
                                                      Wq, Wk, Wv, Qg, Kg, Vt);
    cvt_wo<<<dim3(1024), dim3(256), 0, stream>>>(Wo, WoH);
    attn_kernel<<<dim3(1024), dim3(256), 0, stream>>>(Qg, Kg, Vt, ctx);
    gemm_out<<<dim3(32, 8), dim3(256), 0, stream>>>(ctx, WoH, bo, out);
}

// Round 2
// 144.794 us; speedup vs baseline: 1.3803x; 1.3803x over previous
//
#include <hip/hip_runtime.h>
#include <hip/hip_fp16.h>

typedef _Float16 f16;
typedef _Float16 f16x8 __attribute__((ext_vector_type(8)));
typedef _Float16 f16x4v __attribute__((ext_vector_type(4)));
typedef float f32x4 __attribute__((ext_vector_type(4)));

#define B_ 2
#define S_ 2048
#define E_ 1024
#define H_ 16
#define DH_ 64

__device__ __forceinline__ f32x4 mfma16(f16x8 a, f16x8 b, f32x4 c) {
    return __builtin_amdgcn_mfma_f32_16x16x32_f16(a, b, c, 0, 0, 0);
}

__device__ __forceinline__ f16x8 cvt8(const float* p) {
    float4 v0 = *(const float4*)p;
    float4 v1 = *(const float4*)(p + 4);
    f16x8 r;
    r[0] = (f16)v0.x; r[1] = (f16)v0.y; r[2] = (f16)v0.z; r[3] = (f16)v0.w;
    r[4] = (f16)v1.x; r[5] = (f16)v1.y; r[6] = (f16)v1.z; r[7] = (f16)v1.w;
    return r;
}

// ---------------------------------------------------------------------------
// Kernel 1: per-head projections (unchanged from round 1).
// ---------------------------------------------------------------------------
__global__ __launch_bounds__(256) void proj_kernel(
    const float* __restrict__ q_in, const float* __restrict__ k_in,
    const float* __restrict__ v_in,
    const float* __restrict__ Wq, const float* __restrict__ Wk,
    const float* __restrict__ Wv,
    f16* __restrict__ Qg, f16* __restrict__ Kg, f16* __restrict__ Vt)
{
    int tid = threadIdx.x;
    int lane = tid & 63, wv = tid >> 6;
    int wid = blockIdx.x * 4 + wv;
    int proj = wid >> 12;
    int r = wid & 4095;
    int bh = r >> 7;
    int stile = r & 127;
    int sbase = stile * 16;
    int h = bh & 15;
    int b = bh >> 4;
    int c = lane & 15, g = lane >> 4;

    const float* x; const float* W;
    if (proj == 0)      { x = q_in; W = Wq; }
    else if (proj == 1) { x = k_in; W = Wk; }
    else                { x = v_in; W = Wv; }

    const float* xrow = x + (((size_t)(b * S_ + sbase + c) * H_ + h) << 6);
    f16x8 a0 = cvt8(xrow + g * 8);
    f16x8 a1 = cvt8(xrow + 32 + g * 8);

    f32x4 acc[4] = {};
#pragma unroll
    for (int nt = 0; nt < 4; ++nt) {
        const float* wrow = W + ((nt * 16 + c) << 6);
        f16x8 b0 = cvt8(wrow + g * 8);
        f16x8 b1 = cvt8(wrow + 32 + g * 8);
        acc[nt] = mfma16(a0, b0, acc[nt]);
        acc[nt] = mfma16(a1, b1, acc[nt]);
    }

    if (proj < 2) {
        f16* out = (proj == 0) ? Qg : Kg;
#pragma unroll
        for (int nt = 0; nt < 4; ++nt)
#pragma unroll
            for (int j = 0; j < 4; ++j) {
                int s = sbase + g * 4 + j;
                out[((size_t)bh * S_ + s) * DH_ + nt * 16 + c] = (f16)acc[nt][j];
            }
    } else {
#pragma unroll
        for (int nt = 0; nt < 4; ++nt) {
            f16x4v pk;
            pk[0] = (f16)acc[nt][0]; pk[1] = (f16)acc[nt][1];
            pk[2] = (f16)acc[nt][2]; pk[3] = (f16)acc[nt][3];
            *(f16x4v*)&Vt[((size_t)bh * DH_ + nt * 16 + c) * S_ + sbase + g * 4] = pk;
        }
    }
}

// ---------------------------------------------------------------------------
// Kernel 2: Wo fp32 -> fp16 (unchanged).
// ---------------------------------------------------------------------------
__global__ __launch_bounds__(256) void cvt_wo(const float* __restrict__ W,
                                              f16* __restrict__ out)
{
    int i = blockIdx.x * 256 + threadIdx.x;
    float4 v = *(const float4*)(W + (size_t)i * 4);
    f16x4v o;
    o[0] = (f16)v.x; o[1] = (f16)v.y; o[2] = (f16)v.z; o[3] = (f16)v.w;
    *(f16x4v*)(out + (size_t)i * 4) = o;
}

// ---------------------------------------------------------------------------
// Kernel 3: flash attention, swapped-QK^T layout.
// Block = 4 waves; each wave owns 32 q-rows (2 x 16 subtiles); block = 128 q.
// Per 64-key tile:
//   QK^T = mfma(K, Q): lane (c,g) holds S[key = ks*16+4g+j][q = qs*16+c]
//   -> per-lane softmax over 16 keys + 2 shfl_xor (g-butterfly), once per qs.
//   P packed to f16, written to a per-wave LDS slab (no barrier, wave-local),
//   read back as PV's A-fragment (row = q = c, k = keys).
//   Defer-max: skip accO rescale while tile max grows < 8 (log2 domain).
// ---------------------------------------------------------------------------
#define C1_ 0.18033688011112042f   // log2(e)/sqrt(64)

__global__ __launch_bounds__(256) void attn_kernel(
    const f16* __restrict__ Qg, const f16* __restrict__ Kg,
    const f16* __restrict__ Vt, f16* __restrict__ ctx)
{
    __shared__ __align__(16) f16 Klds[64][72];    // [key][d]
    __shared__ __align__(16) f16 Vtlds[64][72];   // [d][key]
    __shared__ __align__(16) f16 Pl[4][32][72];   // per-wave [q][key] packed f16

    int tid = threadIdx.x, lane = tid & 63, wv = tid >> 6;
    int bx = blockIdx.x;
    int bh = bx >> 4, qt = bx & 15;
    int b = bh >> 4, h = bh & 15;
    int qbase = qt * 128 + wv * 32;
    int c = lane & 15, g = lane >> 4;

    const f16* Qh = Qg + (size_t)bh * S_ * DH_;
    const f16* Kh = Kg + (size_t)bh * S_ * DH_;
    const f16* Vh = Vt + (size_t)bh * DH_ * S_;

    // Q fragments (B-operand): lane (c,g) holds Q[q=qbase+qs*16+c][d=32*hh+8g..]
    f16x8 qf[2][2];
#pragma unroll
    for (int qs = 0; qs < 2; ++qs)
#pragma unroll
        for (int hh = 0; hh < 2; ++hh)
            qf[qs][hh] = *(const f16x8*)(Qh + (size_t)(qbase + qs * 16 + c) * DH_
                                         + hh * 32 + g * 8);

    float m2[2] = {-1e30f, -1e30f};
    float lr[2] = {0.f, 0.f};
    f32x4 accO[2][4] = {};

#pragma unroll 1
    for (int kt = 0; kt < 32; ++kt) {
        int kbase = kt * 64;
        __syncthreads();
#pragma unroll
        for (int i = 0; i < 2; ++i) {
            int idx = i * 256 + tid;
            int row = idx >> 3, cc = idx & 7;
            *(f16x8*)&Klds[row][cc * 8] =
                *(const f16x8*)(Kh + (size_t)(kbase + row) * DH_ + cc * 8);
            *(f16x8*)&Vtlds[row][cc * 8] =
                *(const f16x8*)(Vh + (size_t)row * S_ + kbase + cc * 8);
        }
        __syncthreads();

        // K fragments (A-operand): lane (c,g) = K[key=ks*16+c][d=32*hh+8g..]
        f16x8 kf[4][2];
#pragma unroll
        for (int ks = 0; ks < 4; ++ks)
#pragma unroll
            for (int hh = 0; hh < 2; ++hh)
                kf[ks][hh] = *(const f16x8*)&Klds[ks * 16 + c][hh * 32 + g * 8];

        // QK^T swapped: accS[qs][ks] -> S[key=ks*16+4g+j][q=qs*16+c]
        f32x4 accS[2][4] = {};
#pragma unroll
        for (int qs = 0; qs < 2; ++qs)
#pragma unroll
            for (int ks = 0; ks < 4; ++ks) {
                accS[qs][ks] = mfma16(kf[ks][0], qf[qs][0], accS[qs][ks]);
                accS[qs][ks] = mfma16(kf[ks][1], qf[qs][1], accS[qs][ks]);
            }

        // online softmax per q-subtile (all state per-lane, q = qs*16 + c)
#pragma unroll
        for (int qs = 0; qs < 2; ++qs) {
            float rmax = accS[qs][0][0];
#pragma unroll
            for (int ks = 0; ks < 4; ++ks)
#pragma unroll
                for (int j = 0; j < 4; ++j)
                    rmax = fmaxf(rmax, accS[qs][ks][j]);
            rmax = fmaxf(rmax, __shfl_xor(rmax, 16));
            rmax = fmaxf(rmax, __shfl_xor(rmax, 32));
            float pm2 = rmax * C1_;

            float al = 1.f;
            if (!__all(pm2 - m2[qs] <= 8.f)) {
                float mn = fmaxf(m2[qs], pm2);
                al = exp2f(m2[qs] - mn);
                m2[qs] = mn;
#pragma unroll
                for (int j = 0; j < 4; ++j) {
                    float aj = __shfl(al, ((lane >> 4) << 2) + j);
#pragma unroll
                    for (int nt = 0; nt < 4; ++nt) accO[qs][nt][j] *= aj;
                }
            }

            float rs = 0.f;
            float p[4][4];
#pragma unroll
            for (int ks = 0; ks < 4; ++ks)
#pragma unroll
                for (int j = 0; j < 4; ++j) {
                    float pv = exp2f(fmaf(accS[qs][ks][j], C1_, -m2[qs]));
                    p[ks][j] = pv; rs += pv;
                }
            rs += __shfl_xor(rs, 16);
            rs += __shfl_xor(rs, 32);
            lr[qs] = lr[qs] * al + rs;

            // pack P -> f16, write to per-wave slab: P[q=qs*16+c][key=16ks+4g+j]
#pragma unroll
            for (int ks = 0; ks < 4; ++ks) {
                f16x4v w;
                w[0] = (f16)p[ks][0]; w[1] = (f16)p[ks][1];
                w[2] = (f16)p[ks][2]; w[3] = (f16)p[ks][3];
                *(f16x4v*)&Pl[wv][qs * 16 + c][ks * 16 + 4 * g] = w;
            }
        }

        // PV: A = P (row=q=c, k=keys 32*kh+8g..), B = Vt (k=keys, col=d=c)
        // wave-local LDS dependency -> compiler inserts lgkmcnt wait, no barrier
#pragma unroll
        for (int kh = 0; kh < 2; ++kh) {
            f16x8 vb[4];
#pragma unroll
            for (int nt = 0; nt < 4; ++nt)
                vb[nt] = *(const f16x8*)&Vtlds[nt * 16 + c][kh * 32 + 8 * g];
#pragma unroll
            for (int qs = 0; qs < 2; ++qs) {
                f16x8 pa = *(const f16x8*)&Pl[wv][qs * 16 + c][kh * 32 + 8 * g];
#pragma unroll
                for (int nt = 0; nt < 4; ++nt)
                    accO[qs][nt] = mfma16(pa, vb[nt], accO[qs][nt]);
            }
        }
    }

    // epilogue: divide by l (broadcast per output row), write ctx
#pragma unroll
    for (int qs = 0; qs < 2; ++qs) {
        float inv = 1.f / lr[qs];
#pragma unroll
        for (int j = 0; j < 4; ++j) {
            float lj = __shfl(inv, ((lane >> 4) << 2) + j);
            int s = qbase + qs * 16 + 4 * g + j;
#pragma unroll
            for (int nt = 0; nt < 4; ++nt)
                ctx[((size_t)b * S_ + s) * E_ + h * DH_ + nt * 16 + c] =
                    (f16)(accO[qs][nt][j] * lj);
        }
    }
}

// ---------------------------------------------------------------------------
// Kernel 4: out = ctx @ Wo^T + bo (unchanged).
// ---------------------------------------------------------------------------
__global__ __launch_bounds__(256) void gemm_out(
    const f16* __restrict__ A,
    const f16* __restrict__ Bw,
    const float* __restrict__ bo,
    float* __restrict__ out)
{
    __shared__ __align__(16) f16 Al[128][32];
    __shared__ __align__(16) f16 Bl[128][32];

    int tid = threadIdx.x, lane = tid & 63, wv = tid >> 6;
    int mbase = blockIdx.x * 128, nbase = blockIdx.y * 128;
    int c = lane & 15, g = lane >> 4;
    int wr = wv >> 1, wc = wv & 1;

    f32x4 acc[4][4] = {};

#pragma unroll 1
    for (int kb = 0; kb < 1024; kb += 32) {
        __syncthreads();
#pragma unroll
        for (int i = 0; i < 2; ++i) {
            int idx = i * 256 + tid;
            int row = idx >> 2, chunk = idx & 3;
            *(f16x8*)&Al[row][chunk * 8] =
                *(const f16x8*)(A + (size_t)(mbase + row) * 1024 + kb + chunk * 8);
            *(f16x8*)&Bl[row][chunk * 8] =
                *(const f16x8*)(Bw + (size_t)(nbase + row) * 1024 + kb + chunk * 8);
        }
        __syncthreads();

        f16x8 af[4], bf[4];
#pragma unroll
        for (int mi = 0; mi < 4; ++mi)
            af[mi] = *(const f16x8*)&Al[wr * 64 + mi * 16 + c][g * 8];
#pragma unroll
        for (int ni = 0; ni < 4; ++ni)
            bf[ni] = *(const f16x8*)&Bl[wc * 64 + ni * 16 + c][g * 8];
#pragma unroll
        for (int mi = 0; mi < 4; ++mi)
#pragma unroll
            for (int ni = 0; ni < 4; ++ni)
                acc[mi][ni] = mfma16(af[mi], bf[ni], acc[mi][ni]);
    }

#pragma unroll
    for (int ni = 0; ni < 4; ++ni) {
        float bias = bo[nbase + wc * 64 + ni * 16 + c];
#pragma unroll
        for (int mi = 0; mi < 4; ++mi)
#pragma unroll
            for (int j = 0; j < 4; ++j) {
                int m = mbase + wr * 64 + mi * 16 + g * 4 + j;
                out[(size_t)m * 1024 + nbase + wc * 64 + ni * 16 + c] =
                    acc[mi][ni][j] + bias;
            }
    }
}

extern "C" void kernel_launch(void* const* d_in, const int* in_sizes, int n_in,
                              void* d_out, int out_size, void* d_ws, size_t ws_size,
                              hipStream_t stream)
{
    const float* k_in = (const float*)d_in[0];
    const float* q_in = (const float*)d_in[1];
    const float* v_in = (const float*)d_in[2];
    const float* Wq   = (const float*)d_in[3];
    const float* Wk   = (const float*)d_in[4];
    const float* Wv   = (const float*)d_in[5];
    const float* Wo   = (const float*)d_in[6];
    const float* bo   = (const float*)d_in[7];
    float* out = (float*)d_out;

    char* ws = (char*)d_ws;
    f16* Qg  = (f16*)(ws);
    f16* Kg  = (f16*)(ws + (8u << 20));
    f16* Vt  = (f16*)(ws + (16u << 20));
    f16* ctx = (f16*)(ws + (24u << 20));
    f16* WoH = (f16*)(ws + (32u << 20));

    proj_kernel<<<dim3(3072), dim3(256), 0, stream>>>(q_in, k_in, v_in,
                                                      Wq, Wk, Wv, Qg, Kg, Vt);
    cvt_wo<<<dim3(1024), dim3(256), 0, stream>>>(Wo, WoH);
    attn_kernel<<<dim3(512), dim3(256), 0, stream>>>(Qg, Kg, Vt, ctx);
    gemm_out<<<dim3(32, 8), dim3(256), 0, stream>>>(ctx, WoH, bo, out);
}

// Round 3
// 121.076 us; speedup vs baseline: 1.6507x; 1.1959x over previous
//
#include <hip/hip_runtime.h>
#include <hip/hip_fp16.h>

typedef _Float16 f16;
typedef _Float16 f16x8 __attribute__((ext_vector_type(8)));
typedef _Float16 f16x4v __attribute__((ext_vector_type(4)));
typedef float f32x4 __attribute__((ext_vector_type(4)));

#define B_ 2
#define S_ 2048
#define E_ 1024
#define H_ 16
#define DH_ 64

__device__ __forceinline__ f32x4 mfma16(f16x8 a, f16x8 b, f32x4 c) {
    return __builtin_amdgcn_mfma_f32_16x16x32_f16(a, b, c, 0, 0, 0);
}

__device__ __forceinline__ f16x8 cvt8(const float* p) {
    float4 v0 = *(const float4*)p;
    float4 v1 = *(const float4*)(p + 4);
    f16x8 r;
    r[0] = (f16)v0.x; r[1] = (f16)v0.y; r[2] = (f16)v0.z; r[3] = (f16)v0.w;
    r[4] = (f16)v1.x; r[5] = (f16)v1.y; r[6] = (f16)v1.z; r[7] = (f16)v1.w;
    return r;
}

// ---------------------------------------------------------------------------
// Kernel 1: per-head projections (unchanged).
// ---------------------------------------------------------------------------
__global__ __launch_bounds__(256) void proj_kernel(
    const float* __restrict__ q_in, const float* __restrict__ k_in,
    const float* __restrict__ v_in,
    const float* __restrict__ Wq, const float* __restrict__ Wk,
    const float* __restrict__ Wv,
    f16* __restrict__ Qg, f16* __restrict__ Kg, f16* __restrict__ Vt)
{
    int tid = threadIdx.x;
    int lane = tid & 63, wv = tid >> 6;
    int wid = blockIdx.x * 4 + wv;
    int proj = wid >> 12;
    int r = wid & 4095;
    int bh = r >> 7;
    int stile = r & 127;
    int sbase = stile * 16;
    int h = bh & 15;
    int b = bh >> 4;
    int c = lane & 15, g = lane >> 4;

    const float* x; const float* W;
    if (proj == 0)      { x = q_in; W = Wq; }
    else if (proj == 1) { x = k_in; W = Wk; }
    else                { x = v_in; W = Wv; }

    const float* xrow = x + (((size_t)(b * S_ + sbase + c) * H_ + h) << 6);
    f16x8 a0 = cvt8(xrow + g * 8);
    f16x8 a1 = cvt8(xrow + 32 + g * 8);

    f32x4 acc[4] = {};
#pragma unroll
    for (int nt = 0; nt < 4; ++nt) {
        const float* wrow = W + ((nt * 16 + c) << 6);
        f16x8 b0 = cvt8(wrow + g * 8);
        f16x8 b1 = cvt8(wrow + 32 + g * 8);
        acc[nt] = mfma16(a0, b0, acc[nt]);
        acc[nt] = mfma16(a1, b1, acc[nt]);
    }

    if (proj < 2) {
        f16* out = (proj == 0) ? Qg : Kg;
#pragma unroll
        for (int nt = 0; nt < 4; ++nt)
#pragma unroll
            for (int j = 0; j < 4; ++j) {
                int s = sbase + g * 4 + j;
                out[((size_t)bh * S_ + s) * DH_ + nt * 16 + c] = (f16)acc[nt][j];
            }
    } else {
#pragma unroll
        for (int nt = 0; nt < 4; ++nt) {
            f16x4v pk;
            pk[0] = (f16)acc[nt][0]; pk[1] = (f16)acc[nt][1];
            pk[2] = (f16)acc[nt][2]; pk[3] = (f16)acc[nt][3];
            *(f16x4v*)&Vt[((size_t)bh * DH_ + nt * 16 + c) * S_ + sbase + g * 4] = pk;
        }
    }
}

// ---------------------------------------------------------------------------
// Kernel 2: Wo fp32 -> fp16 (unchanged).
// ---------------------------------------------------------------------------
__global__ __launch_bounds__(256) void cvt_wo(const float* __restrict__ W,
                                              f16* __restrict__ out)
{
    int i = blockIdx.x * 256 + threadIdx.x;
    float4 v = *(const float4*)(W + (size_t)i * 4);
    f16x4v o;
    o[0] = (f16)v.x; o[1] = (f16)v.y; o[2] = (f16)v.z; o[3] = (f16)v.w;
    *(f16x4v*)(out + (size_t)i * 4) = o;
}

// ---------------------------------------------------------------------------
// Kernel 3: flash attention. 512 threads = 8 waves, each wave owns 16 q-rows
// (block = 128 q). K/V double-buffered in XOR-swizzled LDS (128B rows,
// f16col ^= (row&7)<<3), ONE barrier per 64-key tile, next-tile global loads
// issued before compute. Swapped QK^T -> per-lane softmax (q = lane&15),
// 2 shfl_xor butterflies. P through per-wave swizzled LDS slab (barrier-free).
// Defer-max rescale (THR=8, log2 domain).
// ---------------------------------------------------------------------------
#define C1_ 0.18033688011112042f   // log2(e)/sqrt(64)

__global__ __launch_bounds__(512, 4) void attn_kernel(
    const f16* __restrict__ Qg, const f16* __restrict__ Kg,
    const f16* __restrict__ Vt, f16* __restrict__ ctx)
{
    __shared__ __align__(16) f16 Kl[2][64 * 64];   // [key][d], swizzled
    __shared__ __align__(16) f16 Vl[2][64 * 64];   // [d][key], swizzled
    __shared__ __align__(16) f16 Pl[8][16 * 64];   // per-wave [q][key], swizzled

    int tid = threadIdx.x, lane = tid & 63, wv = tid >> 6;
    int bx = blockIdx.x;
    int bh = bx >> 4, qt = bx & 15;
    int b = bh >> 4, h = bh & 15;
    int qbase = qt * 128 + wv * 16;
    int c = lane & 15, g = lane >> 4;
    int swz = (c & 7) << 3;               // f16-unit XOR for fragment accesses

    const f16* Qh = Qg + (size_t)bh * S_ * DH_;
    const f16* Kh = Kg + (size_t)bh * S_ * DH_;
    const f16* Vh = Vt + (size_t)bh * DH_ * S_;

    // staging: 512 threads x 16B cover one 64x64 f16 tile
    int srow = tid >> 3, scc = tid & 7;
    int sdst = srow * 64 + ((scc * 8) ^ ((srow & 7) << 3));
    const f16* ksrc = Kh + (size_t)srow * DH_ + scc * 8;       // + kbase*DH_
    const f16* vsrc = Vh + (size_t)srow * S_ + scc * 8;        // + kbase

    // Q fragments (B-operand): lane holds Q[q=qbase+c][d=32*hh+8g..]
    f16x8 qf[2];
#pragma unroll
    for (int hh = 0; hh < 2; ++hh)
        qf[hh] = *(const f16x8*)(Qh + (size_t)(qbase + c) * DH_ + hh * 32 + g * 8);

    float m2 = -1e30f, lr = 0.f;
    f32x4 accO[4] = {};

    // prologue: stage tile 0
    f16x8 kreg = *(const f16x8*)ksrc;
    f16x8 vreg = *(const f16x8*)vsrc;
    *(f16x8*)&Kl[0][sdst] = kreg;
    *(f16x8*)&Vl[0][sdst] = vreg;
    __syncthreads();

    int cur = 0;
#pragma unroll 1
    for (int kt = 0; kt < 32; ++kt) {
        // issue next-tile loads early (latency hidden under compute)
        if (kt < 31) {
            kreg = *(const f16x8*)(ksrc + (size_t)(kt + 1) * 64 * DH_);
            vreg = *(const f16x8*)(vsrc + (kt + 1) * 64);
        }

        const f16* KA = &Kl[cur][0];
        const f16* VA = &Vl[cur][0];

        // QK^T swapped: accS[ks] -> S[key=16ks+4g+j][q=c]
        f32x4 accS[4] = {};
#pragma unroll
        for (int ks = 0; ks < 4; ++ks) {
            f16x8 k0 = *(const f16x8*)&KA[(ks * 16 + c) * 64 + ((8 * g) ^ swz)];
            f16x8 k1 = *(const f16x8*)&KA[(ks * 16 + c) * 64 + ((32 + 8 * g) ^ swz)];
            accS[ks] = mfma16(k0, qf[0], accS[ks]);
            accS[ks] = mfma16(k1, qf[1], accS[ks]);
        }

        // per-lane online softmax (q = c); butterfly only over g (xor 16,32)
        float rmax = fmaxf(fmaxf(accS[0][0], accS[0][1]),
                           fmaxf(accS[0][2], accS[0][3]));
#pragma unroll
        for (int ks = 1; ks < 4; ++ks)
#pragma unroll
            for (int j = 0; j < 4; ++j) rmax = fmaxf(rmax, accS[ks][j]);
        rmax = fmaxf(rmax, __shfl_xor(rmax, 16));
        rmax = fmaxf(rmax, __shfl_xor(rmax, 32));
        float pm2 = rmax * C1_;

        float al = 1.f;
        if (!__all(pm2 - m2 <= 8.f)) {
            float mn = fmaxf(m2, pm2);
            al = exp2f(m2 - mn);
            m2 = mn;
#pragma unroll
            for (int j = 0; j < 4; ++j) {
                float aj = __shfl(al, 4 * g + j);
#pragma unroll
                for (int nt = 0; nt < 4; ++nt) accO[nt][j] *= aj;
            }
        }

        float rs = 0.f;
        float p[4][4];
#pragma unroll
        for (int ks = 0; ks < 4; ++ks)
#pragma unroll
            for (int j = 0; j < 4; ++j) {
                float pv = exp2f(fmaf(accS[ks][j], C1_, -m2));
                p[ks][j] = pv; rs += pv;
            }
        rs += __shfl_xor(rs, 16);
        rs += __shfl_xor(rs, 32);
        lr = lr * al + rs;

        // pack P -> per-wave slab: Pl[q=c][key=16ks+4g+j], swizzled
#pragma unroll
        for (int ks = 0; ks < 4; ++ks) {
            f16x4v w;
            w[0] = (f16)p[ks][0]; w[1] = (f16)p[ks][1];
            w[2] = (f16)p[ks][2]; w[3] = (f16)p[ks][3];
            *(f16x4v*)&Pl[wv][c * 64 + ((16 * ks + 4 * g) ^ swz)] = w;
        }

        // PV: A = P (row=q=c, k=keys), B = Vt rows (d, keys). wave-local dep.
#pragma unroll
        for (int kh = 0; kh < 2; ++kh) {
            f16x8 pa = *(const f16x8*)&Pl[wv][c * 64 + ((32 * kh + 8 * g) ^ swz)];
#pragma unroll
            for (int nt = 0; nt < 4; ++nt) {
                f16x8 vb = *(const f16x8*)&VA[(nt * 16 + c) * 64
                                              + ((32 * kh + 8 * g) ^ swz)];
                accO[nt] = mfma16(pa, vb, accO[nt]);
            }
        }

        // write next tile into the other buffer; single barrier
        if (kt < 31) {
            *(f16x8*)&Kl[cur ^ 1][sdst] = kreg;
            *(f16x8*)&Vl[cur ^ 1][sdst] = vreg;
            __syncthreads();
        }
        cur ^= 1;
    }

    // epilogue: divide by l (broadcast per output row q = 4g+j), write ctx
    float inv = 1.f / lr;
#pragma unroll
    for (int j = 0; j < 4; ++j) {
        float lj = __shfl(inv, 4 * g + j);
        int s = qbase + 4 * g + j;
#pragma unroll
        for (int nt = 0; nt < 4; ++nt)
            ctx[((size_t)b * S_ + s) * E_ + h * DH_ + nt * 16 + c] =
                (f16)(accO[nt][j] * lj);
    }
}

// ---------------------------------------------------------------------------
// Kernel 4: out = ctx @ Wo^T + bo. 128x64 tiles, BK=64, XOR-swizzled LDS,
// double-buffered, ONE barrier per K-step. 4 waves, each 64x32 output.
// ---------------------------------------------------------------------------
__global__ __launch_bounds__(256) void gemm_out(
    const f16* __restrict__ A,    // ctx [4096][1024]
    const f16* __restrict__ Bw,   // Wo f16 [1024][1024]
    const float* __restrict__ bo,
    float* __restrict__ out)      // [4096][1024] fp32
{
    __shared__ __align__(16) f16 Al[2][128 * 64];
    __shared__ __align__(16) f16 Bl[2][64 * 64];

    int tid = threadIdx.x, lane = tid & 63, wv = tid >> 6;
    int mbase = blockIdx.x * 128, nbase = blockIdx.y * 64;
    int c = lane & 15, g = lane >> 4;
    int wr = wv >> 1, wc = wv & 1;
    int swz = (c & 7) << 3;

    // staging: A tile 128x64 f16 = 1024 x 16B slots (4/thread);
    //          B tile 64x64 = 512 slots (2/thread)
    int arow[4], adst[4]; const f16* asrc[4];
#pragma unroll
    for (int i = 0; i < 4; ++i) {
        int slot = tid + i * 256;
        arow[i] = slot >> 3;
        int cc = slot & 7;
        adst[i] = arow[i] * 64 + ((cc * 8) ^ ((arow[i] & 7) << 3));
        asrc[i] = A + (size_t)(mbase + arow[i]) * 1024 + cc * 8;
    }
    int bdst[2]; const f16* bsrc[2];
#pragma unroll
    for (int i = 0; i < 2; ++i) {
        int slot = tid + i * 256;
        int row = slot >> 3, cc = slot & 7;
        bdst[i] = row * 64 + ((cc * 8) ^ ((row & 7) << 3));
        bsrc[i] = Bw + (size_t)(nbase + row) * 1024 + cc * 8;
    }

    f32x4 acc[4][2] = {};

    // prologue: stage K-step 0
    f16x8 areg[4], breg[2];
#pragma unroll
    for (int i = 0; i < 4; ++i) areg[i] = *(const f16x8*)asrc[i];
#pragma unroll
    for (int i = 0; i < 2; ++i) breg[i] = *(const f16x8*)bsrc[i];
#pragma unroll
    for (int i = 0; i < 4; ++i) *(f16x8*)&Al[0][adst[i]] = areg[i];
#pragma unroll
    for (int i = 0; i < 2; ++i) *(f16x8*)&Bl[0][bdst[i]] = breg[i];
    __syncthreads();

    int cur = 0;
#pragma unroll 1
    for (int ks = 0; ks < 16; ++ks) {
        if (ks < 15) {
#pragma unroll
            for (int i = 0; i < 4; ++i)
                areg[i] = *(const f16x8*)(asrc[i] + (ks + 1) * 64);
#pragma unroll
            for (int i = 0; i < 2; ++i)
                breg[i] = *(const f16x8*)(bsrc[i] + (ks + 1) * 64);
        }

        const f16* AA = &Al[cur][0];
        const f16* BB = &Bl[cur][0];
#pragma unroll
        for (int kk = 0; kk < 2; ++kk) {
            f16x8 af[4], bf[2];
#pragma unroll
            for (int mi = 0; mi < 4; ++mi)
                af[mi] = *(const f16x8*)&AA[(wr * 64 + mi * 16 + c) * 64
                                            + ((32 * kk + 8 * g) ^ swz)];
#pragma unroll
            for (int ni = 0; ni < 2; ++ni)
                bf[ni] = *(const f16x8*)&BB[(wc * 32 + ni * 16 + c) * 64
                                            + ((32 * kk + 8 * g) ^ swz)];
#pragma unroll
            for (int mi = 0; mi < 4; ++mi)
#pragma unroll
                for (int ni = 0; ni < 2; ++ni)
                    acc[mi][ni] = mfma16(af[mi], bf[ni], acc[mi][ni]);
        }

        if (ks < 15) {
#pragma unroll
            for (int i = 0; i < 4; ++i) *(f16x8*)&Al[cur ^ 1][adst[i]] = areg[i];
#pragma unroll
            for (int i = 0; i < 2; ++i) *(f16x8*)&Bl[cur ^ 1][bdst[i]] = breg[i];
            __syncthreads();
        }
        cur ^= 1;
    }

    // epilogue: + bias, fp32 store
#pragma unroll
    for (int ni = 0; ni < 2; ++ni) {
        float bias = bo[nbase + wc * 32 + ni * 16 + c];
#pragma unroll
        for (int mi = 0; mi < 4; ++mi)
#pragma unroll
            for (int j = 0; j < 4; ++j) {
                int m = mbase + wr * 64 + mi * 16 + g * 4 + j;
                out[(size_t)m * 1024 + nbase + wc * 32 + ni * 16 + c] =
                    acc[mi][ni][j] + bias;
            }
    }
}

extern "C" void kernel_launch(void* const* d_in, const int* in_sizes, int n_in,
                              void* d_out, int out_size, void* d_ws, size_t ws_size,
                              hipStream_t stream)
{
    const float* k_in = (const float*)d_in[0];
    const float* q_in = (const float*)d_in[1];
    const float* v_in = (const float*)d_in[2];
    const float* Wq   = (const float*)d_in[3];
    const float* Wk   = (const float*)d_in[4];
    const float* Wv   = (const float*)d_in[5];
    const float* Wo   = (const float*)d_in[6];
    const float* bo   = (const float*)d_in[7];
    float* out = (float*)d_out;

    char* ws = (char*)d_ws;
    f16* Qg  = (f16*)(ws);
    f16* Kg  = (f16*)(ws + (8u << 20));
    f16* Vt  = (f16*)(ws + (16u << 20));
    f16* ctx = (f16*)(ws + (24u << 20));
    f16* WoH = (f16*)(ws + (32u << 20));

    proj_kernel<<<dim3(3072), dim3(256), 0, stream>>>(q_in, k_in, v_in,
                                                      Wq, Wk, Wv, Qg, Kg, Vt);
    cvt_wo<<<dim3(1024), dim3(256), 0, stream>>>(Wo, WoH);
    attn_kernel<<<dim3(512), dim3(512), 0, stream>>>(Qg, Kg, Vt, ctx);
    gemm_out<<<dim3(32, 16), dim3(256), 0, stream>>>(ctx, WoH, bo, out);
}

// Round 4
// 118.961 us; speedup vs baseline: 1.6800x; 1.0178x over previous
//
#include <hip/hip_runtime.h>
#include <hip/hip_fp16.h>

typedef _Float16 f16;
typedef _Float16 f16x8 __attribute__((ext_vector_type(8)));
typedef _Float16 f16x4v __attribute__((ext_vector_type(4)));
typedef float f32x4 __attribute__((ext_vector_type(4)));

#define B_ 2
#define S_ 2048
#define E_ 1024
#define H_ 16
#define DH_ 64

__device__ __forceinline__ f32x4 mfma16(f16x8 a, f16x8 b, f32x4 c) {
    return __builtin_amdgcn_mfma_f32_16x16x32_f16(a, b, c, 0, 0, 0);
}

__device__ __forceinline__ f16x8 cvt8(const float* p) {
    float4 v0 = *(const float4*)p;
    float4 v1 = *(const float4*)(p + 4);
    f16x8 r;
    r[0] = (f16)v0.x; r[1] = (f16)v0.y; r[2] = (f16)v0.z; r[3] = (f16)v0.w;
    r[4] = (f16)v1.x; r[5] = (f16)v1.y; r[6] = (f16)v1.z; r[7] = (f16)v1.w;
    return r;
}

// ---------------------------------------------------------------------------
// Kernel 1: per-head projections (unchanged).
// ---------------------------------------------------------------------------
__global__ __launch_bounds__(256) void proj_kernel(
    const float* __restrict__ q_in, const float* __restrict__ k_in,
    const float* __restrict__ v_in,
    const float* __restrict__ Wq, const float* __restrict__ Wk,
    const float* __restrict__ Wv,
    f16* __restrict__ Qg, f16* __restrict__ Kg, f16* __restrict__ Vt)
{
    int tid = threadIdx.x;
    int lane = tid & 63, wv = tid >> 6;
    int wid = blockIdx.x * 4 + wv;
    int proj = wid >> 12;
    int r = wid & 4095;
    int bh = r >> 7;
    int stile = r & 127;
    int sbase = stile * 16;
    int h = bh & 15;
    int b = bh >> 4;
    int c = lane & 15, g = lane >> 4;

    const float* x; const float* W;
    if (proj == 0)      { x = q_in; W = Wq; }
    else if (proj == 1) { x = k_in; W = Wk; }
    else                { x = v_in; W = Wv; }

    const float* xrow = x + (((size_t)(b * S_ + sbase + c) * H_ + h) << 6);
    f16x8 a0 = cvt8(xrow + g * 8);
    f16x8 a1 = cvt8(xrow + 32 + g * 8);

    f32x4 acc[4] = {};
#pragma unroll
    for (int nt = 0; nt < 4; ++nt) {
        const float* wrow = W + ((nt * 16 + c) << 6);
        f16x8 b0 = cvt8(wrow + g * 8);
        f16x8 b1 = cvt8(wrow + 32 + g * 8);
        acc[nt] = mfma16(a0, b0, acc[nt]);
        acc[nt] = mfma16(a1, b1, acc[nt]);
    }

    if (proj < 2) {
        f16* out = (proj == 0) ? Qg : Kg;
#pragma unroll
        for (int nt = 0; nt < 4; ++nt)
#pragma unroll
            for (int j = 0; j < 4; ++j) {
                int s = sbase + g * 4 + j;
                out[((size_t)bh * S_ + s) * DH_ + nt * 16 + c] = (f16)acc[nt][j];
            }
    } else {
#pragma unroll
        for (int nt = 0; nt < 4; ++nt) {
            f16x4v pk;
            pk[0] = (f16)acc[nt][0]; pk[1] = (f16)acc[nt][1];
            pk[2] = (f16)acc[nt][2]; pk[3] = (f16)acc[nt][3];
            *(f16x4v*)&Vt[((size_t)bh * DH_ + nt * 16 + c) * S_ + sbase + g * 4] = pk;
        }
    }
}

// ---------------------------------------------------------------------------
// Kernel 2: flash attention. 512 thr = 8 waves x 16 q-rows (block = 128 q).
// KT=128 keys per iteration (2 x 64-key subtiles), ONE barrier per iter.
// Double-buffered swizzled LDS. Swapped QK^T -> per-lane softmax with:
//   - per-lane l partials (sum-reduce ONCE at epilogue)
//   - max-reduce only when defer-max check triggers (common path: 0 shfl)
// setprio(1) around MFMA clusters.
// ---------------------------------------------------------------------------
#define C1_ 0.18033688011112042f   // log2(e)/sqrt(64)

__global__ __launch_bounds__(512, 4) void attn_kernel(
    const f16* __restrict__ Qg, const f16* __restrict__ Kg,
    const f16* __restrict__ Vt, f16* __restrict__ ctx)
{
    __shared__ __align__(16) f16 Kl[2][128 * 64];  // [key][d], swizzled
    __shared__ __align__(16) f16 Vl[2][64 * 128];  // [d][key], swizzled
    __shared__ __align__(16) f16 Pl[8][16 * 64];   // per-wave [q][key]

    int tid = threadIdx.x, lane = tid & 63, wv = tid >> 6;
    int bx = blockIdx.x;
    int bh = bx >> 4, qt = bx & 15;
    int b = bh >> 4, h = bh & 15;
    int qbase = qt * 128 + wv * 16;
    int c = lane & 15, g = lane >> 4;
    int swz = (c & 7) << 3;

    const f16* Qh = Qg + (size_t)bh * S_ * DH_;
    const f16* Kh = Kg + (size_t)bh * S_ * DH_;
    const f16* Vh = Vt + (size_t)bh * DH_ * S_;

    // staging: K tile 128x64 f16 = 1024 16B slots; V tile 64x128 = 1024 slots.
    // thread handles slots tid and tid+512 of each.
    int s0 = tid, s1 = tid + 512;
    int kr0 = s0 >> 3, kc0 = s0 & 7, kr1 = s1 >> 3, kc1 = s1 & 7;
    int kd0 = kr0 * 64 + ((kc0 * 8) ^ ((kr0 & 7) << 3));
    int kd1 = kr1 * 64 + ((kc1 * 8) ^ ((kr1 & 7) << 3));
    const f16* ksp0 = Kh + kr0 * 64 + kc0 * 8;
    const f16* ksp1 = Kh + kr1 * 64 + kc1 * 8;
    int vr0 = s0 >> 4, vc0 = s0 & 15, vr1 = s1 >> 4, vc1 = s1 & 15;
    int vd0 = vr0 * 128 + ((vc0 * 8) ^ ((vr0 & 7) << 3));
    int vd1 = vr1 * 128 + ((vc1 * 8) ^ ((vr1 & 7) << 3));
    const f16* vsp0 = Vh + vr0 * S_ + vc0 * 8;
    const f16* vsp1 = Vh + vr1 * S_ + vc1 * 8;

    // Q fragments (B-operand): lane holds Q[q=qbase+c][d=32*hh+8g..]
    f16x8 qf[2];
#pragma unroll
    for (int hh = 0; hh < 2; ++hh)
        qf[hh] = *(const f16x8*)(Qh + (size_t)(qbase + c) * DH_ + hh * 32 + g * 8);

    float m2 = -1e30f, lr = 0.f;
    f32x4 accO[4] = {};

    // prologue: stage tile 0
    f16x8 kreg0 = *(const f16x8*)ksp0, kreg1 = *(const f16x8*)ksp1;
    f16x8 vreg0 = *(const f16x8*)vsp0, vreg1 = *(const f16x8*)vsp1;
    *(f16x8*)&Kl[0][kd0] = kreg0; *(f16x8*)&Kl[0][kd1] = kreg1;
    *(f16x8*)&Vl[0][vd0] = vreg0; *(f16x8*)&Vl[0][vd1] = vreg1;
    __syncthreads();

    int cur = 0;
#pragma unroll 1
    for (int kt = 0; kt < 16; ++kt) {
        // issue next-tile loads early
        if (kt < 15) {
            int ko = (kt + 1) * 128 * 64, vo = (kt + 1) * 128;
            kreg0 = *(const f16x8*)(ksp0 + ko);
            kreg1 = *(const f16x8*)(ksp1 + ko);
            vreg0 = *(const f16x8*)(vsp0 + vo);
            vreg1 = *(const f16x8*)(vsp1 + vo);
        }

        const f16* KA = &Kl[cur][0];
        const f16* VA = &Vl[cur][0];

#pragma unroll
        for (int st = 0; st < 2; ++st) {
            // QK^T swapped: accS[ks] -> S[key=st*64+16ks+4g+j][q=c]
            f32x4 accS[4] = {};
            __builtin_amdgcn_s_setprio(1);
#pragma unroll
            for (int ks = 0; ks < 4; ++ks) {
                int krow = (st * 64 + ks * 16 + c) * 64;
                f16x8 k0 = *(const f16x8*)&KA[krow + ((8 * g) ^ swz)];
                f16x8 k1 = *(const f16x8*)&KA[krow + ((32 + 8 * g) ^ swz)];
                accS[ks] = mfma16(k0, qf[0], accS[ks]);
                accS[ks] = mfma16(k1, qf[1], accS[ks]);
            }
            __builtin_amdgcn_s_setprio(0);

            // per-lane max; cross-lane reduce only on defer-max trigger
            float rmax = fmaxf(fmaxf(accS[0][0], accS[0][1]),
                               fmaxf(accS[0][2], accS[0][3]));
#pragma unroll
            for (int ks = 1; ks < 4; ++ks)
#pragma unroll
                for (int j = 0; j < 4; ++j) rmax = fmaxf(rmax, accS[ks][j]);

            if (!__all(fmaf(rmax, C1_, -m2) <= 8.f)) {
                float mx = fmaxf(rmax, __shfl_xor(rmax, 16));
                mx = fmaxf(mx, __shfl_xor(mx, 32));
                float mn = fmaxf(m2, mx * C1_);
                float al = exp2f(m2 - mn);
                m2 = mn;
                lr *= al;
#pragma unroll
                for (int j = 0; j < 4; ++j) {
                    float aj = __shfl(al, 4 * g + j);
#pragma unroll
                    for (int nt = 0; nt < 4; ++nt) accO[nt][j] *= aj;
                }
            }

            // exp + per-lane row-sum partial
            float p[4][4];
#pragma unroll
            for (int ks = 0; ks < 4; ++ks)
#pragma unroll
                for (int j = 0; j < 4; ++j) {
                    float pv = exp2f(fmaf(accS[ks][j], C1_, -m2));
                    p[ks][j] = pv; lr += pv;
                }

            // pack P -> per-wave slab: Pl[q=c][key=16ks+4g+j], swizzled
#pragma unroll
            for (int ks = 0; ks < 4; ++ks) {
                f16x4v w;
                w[0] = (f16)p[ks][0]; w[1] = (f16)p[ks][1];
                w[2] = (f16)p[ks][2]; w[3] = (f16)p[ks][3];
                *(f16x4v*)&Pl[wv][c * 64 + ((16 * ks + 4 * g) ^ swz)] = w;
            }

            // PV: A = P (row=q=c, k=keys), B = Vt rows (d, keys)
            __builtin_amdgcn_s_setprio(1);
#pragma unroll
            for (int kh = 0; kh < 2; ++kh) {
                f16x8 pa = *(const f16x8*)&Pl[wv][c * 64 + ((32 * kh + 8 * g) ^ swz)];
#pragma unroll
                for (int nt = 0; nt < 4; ++nt) {
                    f16x8 vb = *(const f16x8*)&VA[(nt * 16 + c) * 128
                                  + ((st * 64 + 32 * kh + 8 * g) ^ swz)];
                    accO[nt] = mfma16(pa, vb, accO[nt]);
                }
            }
            __builtin_amdgcn_s_setprio(0);
        }

        if (kt < 15) {
            *(f16x8*)&Kl[cur ^ 1][kd0] = kreg0; *(f16x8*)&Kl[cur ^ 1][kd1] = kreg1;
            *(f16x8*)&Vl[cur ^ 1][vd0] = vreg0; *(f16x8*)&Vl[cur ^ 1][vd1] = vreg1;
            __syncthreads();
        }
        cur ^= 1;
    }

    // epilogue: reduce l across g, divide, write ctx
    lr += __shfl_xor(lr, 16);
    lr += __shfl_xor(lr, 32);
    float inv = 1.f / lr;
#pragma unroll
    for (int j = 0; j < 4; ++j) {
        float lj = __shfl(inv, 4 * g + j);
        int s = qbase + 4 * g + j;
#pragma unroll
        for (int nt = 0; nt < 4; ++nt)
            ctx[((size_t)b * S_ + s) * E_ + h * DH_ + nt * 16 + c] =
                (f16)(accO[nt][j] * lj);
    }
}

// ---------------------------------------------------------------------------
// Kernel 3: out = ctx @ Wo^T + bo. Wo converted f32->f16 inline in B staging.
// 128x64 tiles, BK=64, swizzled dbuf LDS, 1 barrier/step, setprio on MFMA.
// ---------------------------------------------------------------------------
__global__ __launch_bounds__(256) void gemm_out(
    const f16* __restrict__ A,    // ctx [4096][1024] f16
    const float* __restrict__ Wo, // [1024][1024] f32
    const float* __restrict__ bo,
    float* __restrict__ out)      // [4096][1024] fp32
{
    __shared__ __align__(16) f16 Al[2][128 * 64];
    __shared__ __align__(16) f16 Bl[2][64 * 64];

    int tid = threadIdx.x, lane = tid & 63, wv = tid >> 6;
    int mbase = blockIdx.x * 128, nbase = blockIdx.y * 64;
    int c = lane & 15, g = lane >> 4;
    int wr = wv >> 1, wc = wv & 1;
    int swz = (c & 7) << 3;

    int arow[4], adst[4]; const f16* asrc[4];
#pragma unroll
    for (int i = 0; i < 4; ++i) {
        int slot = tid + i * 256;
        arow[i] = slot >> 3;
        int cc = slot & 7;
        adst[i] = arow[i] * 64 + ((cc * 8) ^ ((arow[i] & 7) << 3));
        asrc[i] = A + (size_t)(mbase + arow[i]) * 1024 + cc * 8;
    }
    int bdst[2]; const float* bsrc[2];
#pragma unroll
    for (int i = 0; i < 2; ++i) {
        int slot = tid + i * 256;
        int row = slot >> 3, cc = slot & 7;
        bdst[i] = row * 64 + ((cc * 8) ^ ((row & 7) << 3));
        bsrc[i] = Wo + (size_t)(nbase + row) * 1024 + cc * 8;
    }

    f32x4 acc[4][2] = {};

    // prologue: stage K-step 0
    f16x8 areg[4], breg[2];
#pragma unroll
    for (int i = 0; i < 4; ++i) areg[i] = *(const f16x8*)asrc[i];
#pragma unroll
    for (int i = 0; i < 2; ++i) breg[i] = cvt8(bsrc[i]);
#pragma unroll
    for (int i = 0; i < 4; ++i) *(f16x8*)&Al[0][adst[i]] = areg[i];
#pragma unroll
    for (int i = 0; i < 2; ++i) *(f16x8*)&Bl[0][bdst[i]] = breg[i];
    __syncthreads();

    int cur = 0;
#pragma unroll 1
    for (int ks = 0; ks < 16; ++ks) {
        if (ks < 15) {
#pragma unroll
            for (int i = 0; i < 4; ++i)
                areg[i] = *(const f16x8*)(asrc[i] + (ks + 1) * 64);
#pragma unroll
            for (int i = 0; i < 2; ++i)
                breg[i] = cvt8(bsrc[i] + (ks + 1) * 64);
        }

        const f16* AA = &Al[cur][0];
        const f16* BB = &Bl[cur][0];
        __builtin_amdgcn_s_setprio(1);
#pragma unroll
        for (int kk = 0; kk < 2; ++kk) {
            f16x8 af[4], bf[2];
#pragma unroll
            for (int mi = 0; mi < 4; ++mi)
                af[mi] = *(const f16x8*)&AA[(wr * 64 + mi * 16 + c) * 64
                                            + ((32 * kk + 8 * g) ^ swz)];
#pragma unroll
            for (int ni = 0; ni < 2; ++ni)
                bf[ni] = *(const f16x8*)&BB[(wc * 32 + ni * 16 + c) * 64
                                            + ((32 * kk + 8 * g) ^ swz)];
#pragma unroll
            for (int mi = 0; mi < 4; ++mi)
#pragma unroll
                for (int ni = 0; ni < 2; ++ni)
                    acc[mi][ni] = mfma16(af[mi], bf[ni], acc[mi][ni]);
        }
        __builtin_amdgcn_s_setprio(0);

        if (ks < 15) {
#pragma unroll
            for (int i = 0; i < 4; ++i) *(f16x8*)&Al[cur ^ 1][adst[i]] = areg[i];
#pragma unroll
            for (int i = 0; i < 2; ++i) *(f16x8*)&Bl[cur ^ 1][bdst[i]] = breg[i];
            __syncthreads();
        }
        cur ^= 1;
    }

    // epilogue: + bias, fp32 store
#pragma unroll
    for (int ni = 0; ni < 2; ++ni) {
        float bias = bo[nbase + wc * 32 + ni * 16 + c];
#pragma unroll
        for (int mi = 0; mi < 4; ++mi)
#pragma unroll
            for (int j = 0; j < 4; ++j) {
                int m = mbase + wr * 64 + mi * 16 + g * 4 + j;
                out[(size_t)m * 1024 + nbase + wc * 32 + ni * 16 + c] =
                    acc[mi][ni][j] + bias;
            }
    }
}

extern "C" void kernel_launch(void* const* d_in, const int* in_sizes, int n_in,
                              void* d_out, int out_size, void* d_ws, size_t ws_size,
                              hipStream_t stream)
{
    const float* k_in = (const float*)d_in[0];
    const float* q_in = (const float*)d_in[1];
    const float* v_in = (const float*)d_in[2];
    const float* Wq   = (const float*)d_in[3];
    const float* Wk   = (const float*)d_in[4];
    const float* Wv   = (const float*)d_in[5];
    const float* Wo   = (const float*)d_in[6];
    const float* bo   = (const float*)d_in[7];
    float* out = (float*)d_out;

    char* ws = (char*)d_ws;
    f16* Qg  = (f16*)(ws);
    f16* Kg  = (f16*)(ws + (8u << 20));
    f16* Vt  = (f16*)(ws + (16u << 20));
    f16* ctx = (f16*)(ws + (24u << 20));

    proj_kernel<<<dim3(3072), dim3(256), 0, stream>>>(q_in, k_in, v_in,
                                                      Wq, Wk, Wv, Qg, Kg, Vt);
    attn_kernel<<<dim3(512), dim3(512), 0, stream>>>(Qg, Kg, Vt, ctx);
    gemm_out<<<dim3(32, 16), dim3(256), 0, stream>>>(ctx, Wo, bo, out);
}

// Round 5
// 114.966 us; speedup vs baseline: 1.7384x; 1.0347x over previous
//
#include <hip/hip_runtime.h>
#include <hip/hip_fp16.h>

typedef _Float16 f16;
typedef _Float16 f16x8 __attribute__((ext_vector_type(8)));
typedef _Float16 f16x4v __attribute__((ext_vector_type(4)));
typedef float f32x4 __attribute__((ext_vector_type(4)));

#define B_ 2
#define S_ 2048
#define E_ 1024
#define H_ 16
#define DH_ 64

__device__ __forceinline__ f32x4 mfma16(f16x8 a, f16x8 b, f32x4 c) {
    return __builtin_amdgcn_mfma_f32_16x16x32_f16(a, b, c, 0, 0, 0);
}

__device__ __forceinline__ f32x4 vmax4(f32x4 a, f32x4 b) {
    f32x4 r;
    r[0] = fmaxf(a[0], b[0]); r[1] = fmaxf(a[1], b[1]);
    r[2] = fmaxf(a[2], b[2]); r[3] = fmaxf(a[3], b[3]);
    return r;
}

__device__ __forceinline__ f16x8 cvt8(const float* p) {
    float4 v0 = *(const float4*)p;
    float4 v1 = *(const float4*)(p + 4);
    f16x8 r;
    r[0] = (f16)v0.x; r[1] = (f16)v0.y; r[2] = (f16)v0.z; r[3] = (f16)v0.w;
    r[4] = (f16)v1.x; r[5] = (f16)v1.y; r[6] = (f16)v1.z; r[7] = (f16)v1.w;
    return r;
}

// ---------------------------------------------------------------------------
// Kernel 1: per-head projections (unchanged).
// ---------------------------------------------------------------------------
__global__ __launch_bounds__(256) void proj_kernel(
    const float* __restrict__ q_in, const float* __restrict__ k_in,
    const float* __restrict__ v_in,
    const float* __restrict__ Wq, const float* __restrict__ Wk,
    const float* __restrict__ Wv,
    f16* __restrict__ Qg, f16* __restrict__ Kg, f16* __restrict__ Vt)
{
    int tid = threadIdx.x;
    int lane = tid & 63, wv = tid >> 6;
    int wid = blockIdx.x * 4 + wv;
    int proj = wid >> 12;
    int r = wid & 4095;
    int bh = r >> 7;
    int stile = r & 127;
    int sbase = stile * 16;
    int h = bh & 15;
    int b = bh >> 4;
    int c = lane & 15, g = lane >> 4;

    const float* x; const float* W;
    if (proj == 0)      { x = q_in; W = Wq; }
    else if (proj == 1) { x = k_in; W = Wk; }
    else                { x = v_in; W = Wv; }

    const float* xrow = x + (((size_t)(b * S_ + sbase + c) * H_ + h) << 6);
    f16x8 a0 = cvt8(xrow + g * 8);
    f16x8 a1 = cvt8(xrow + 32 + g * 8);

    f32x4 acc[4] = {};
#pragma unroll
    for (int nt = 0; nt < 4; ++nt) {
        const float* wrow = W + ((nt * 16 + c) << 6);
        f16x8 b0 = cvt8(wrow + g * 8);
        f16x8 b1 = cvt8(wrow + 32 + g * 8);
        acc[nt] = mfma16(a0, b0, acc[nt]);
        acc[nt] = mfma16(a1, b1, acc[nt]);
    }

    if (proj < 2) {
        f16* out = (proj == 0) ? Qg : Kg;
#pragma unroll
        for (int nt = 0; nt < 4; ++nt)
#pragma unroll
            for (int j = 0; j < 4; ++j) {
                int s = sbase + g * 4 + j;
                out[((size_t)bh * S_ + s) * DH_ + nt * 16 + c] = (f16)acc[nt][j];
            }
    } else {
#pragma unroll
        for (int nt = 0; nt < 4; ++nt) {
            f16x4v pk;
            pk[0] = (f16)acc[nt][0]; pk[1] = (f16)acc[nt][1];
            pk[2] = (f16)acc[nt][2]; pk[3] = (f16)acc[nt][3];
            *(f16x4v*)&Vt[((size_t)bh * DH_ + nt * 16 + c) * S_ + sbase + g * 4] = pk;
        }
    }
}

// ---------------------------------------------------------------------------
// Kernel 2: Wo fp32 -> fp16.
// ---------------------------------------------------------------------------
__global__ __launch_bounds__(256) void cvt_wo(const float* __restrict__ W,
                                              f16* __restrict__ out)
{
    int i = blockIdx.x * 256 + threadIdx.x;
    float4 v = *(const float4*)(W + (size_t)i * 4);
    f16x4v o;
    o[0] = (f16)v.x; o[1] = (f16)v.y; o[2] = (f16)v.z; o[3] = (f16)v.w;
    *(f16x4v*)(out + (size_t)i * 4) = o;
}

// ---------------------------------------------------------------------------
// Kernel 3: flash attention. 512 thr = 8 waves x 16 q-rows (block = 128 q).
// KT=128 keys/iter (2 x 64-key subtiles), 1 barrier/iter, compile-time
// double-buffer (STEP macro, cur is a literal -> imm LDS offsets).
// V tiles split per-subtile with 64-f16 pitch (conflict-clean swizzle).
// XCD-swizzled grid: all 16 q-tiles of a bh on one XCD (K/V L2-resident).
// ---------------------------------------------------------------------------
#define C1_ 0.18033688011112042f   // log2(e)/sqrt(64)

__global__ __launch_bounds__(512, 4) void attn_kernel(
    const f16* __restrict__ Qg, const f16* __restrict__ Kg,
    const f16* __restrict__ Vt, f16* __restrict__ ctx)
{
    __shared__ __align__(16) f16 Kl[2][128 * 64];      // [key][d], swizzled
    __shared__ __align__(16) f16 Vl[2][2][64 * 64];    // [st][d][key], swizzled
    __shared__ __align__(16) f16 Pl[8][16 * 64];       // per-wave [q][key]

    int tid = threadIdx.x, lane = tid & 63, wv = tid >> 6;
    int bid = blockIdx.x;
    int sb = (bid & 7) * 64 + (bid >> 3);      // XCD-contiguous: bh-major
    int bh = sb >> 4, qt = sb & 15;
    int b = bh >> 4, h = bh & 15;
    int qbase = qt * 128 + wv * 16;
    int c = lane & 15, g = lane >> 4;
    int swz = (c & 7) << 3;

    const f16* Qh = Qg + (size_t)bh * S_ * DH_;
    const f16* Kh = Kg + (size_t)bh * S_ * DH_;
    const f16* Vh = Vt + (size_t)bh * DH_ * S_;

    // staging: K tile 128x64 = 1024 16B slots; V tile 64x128 = 1024 slots.
    int s0 = tid, s1 = tid + 512;
    int kr0 = s0 >> 3, kc0 = s0 & 7, kr1 = s1 >> 3, kc1 = s1 & 7;
    int kd0 = kr0 * 64 + ((kc0 * 8) ^ ((kr0 & 7) << 3));
    int kd1 = kr1 * 64 + ((kc1 * 8) ^ ((kr1 & 7) << 3));
    const f16* ksp0 = Kh + kr0 * 64 + kc0 * 8;
    const f16* ksp1 = Kh + kr1 * 64 + kc1 * 8;
    int vr0 = s0 >> 4, vc0 = s0 & 15, vr1 = s1 >> 4, vc1 = s1 & 15;
    int vst0 = vc0 >> 3, vst1 = vc1 >> 3;
    int vd0 = vr0 * 64 + (((vc0 & 7) * 8) ^ ((vr0 & 7) << 3));
    int vd1 = vr1 * 64 + (((vc1 & 7) * 8) ^ ((vr1 & 7) << 3));
    const f16* vsp0 = Vh + vr0 * S_ + vc0 * 8;
    const f16* vsp1 = Vh + vr1 * S_ + vc1 * 8;

    // Q fragments (B-operand): lane holds Q[q=qbase+c][d=32*hh+8g..]
    f16x8 qf[2];
#pragma unroll
    for (int hh = 0; hh < 2; ++hh)
        qf[hh] = *(const f16x8*)(Qh + (size_t)(qbase + c) * DH_ + hh * 32 + g * 8);

    float m2 = -1e30f;
    f32x4 lrv = {};
    f32x4 accO[4] = {};
    f16x8 kreg0, kreg1, vreg0, vreg1;

    // prologue: stage tile 0
    kreg0 = *(const f16x8*)ksp0; kreg1 = *(const f16x8*)ksp1;
    vreg0 = *(const f16x8*)vsp0; vreg1 = *(const f16x8*)vsp1;
    *(f16x8*)&Kl[0][kd0] = kreg0; *(f16x8*)&Kl[0][kd1] = kreg1;
    *(f16x8*)&Vl[0][vst0][vd0] = vreg0; *(f16x8*)&Vl[0][vst1][vd1] = vreg1;
    __syncthreads();

#define ATTN_STEP(CUR, T, STAGE)                                               \
    do {                                                                       \
        if (STAGE) {                                                           \
            int ko = ((T) + 1) * 128 * 64, vo = ((T) + 1) * 128;               \
            kreg0 = *(const f16x8*)(ksp0 + ko);                                \
            kreg1 = *(const f16x8*)(ksp1 + ko);                                \
            vreg0 = *(const f16x8*)(vsp0 + vo);                                \
            vreg1 = *(const f16x8*)(vsp1 + vo);                                \
        }                                                                      \
        _Pragma("unroll")                                                      \
        for (int st = 0; st < 2; ++st) {                                       \
            f32x4 accS[4] = {};                                                \
            __builtin_amdgcn_s_setprio(1);                                     \
            _Pragma("unroll")                                                  \
            for (int ks = 0; ks < 4; ++ks) {                                   \
                int krow = (st * 64 + ks * 16 + c) * 64;                       \
                f16x8 k0 = *(const f16x8*)&Kl[CUR][krow + ((8 * g) ^ swz)];    \
                f16x8 k1 = *(const f16x8*)&Kl[CUR][krow + ((32 + 8 * g) ^ swz)];\
                accS[ks] = mfma16(k0, qf[0], accS[ks]);                        \
                accS[ks] = mfma16(k1, qf[1], accS[ks]);                        \
            }                                                                  \
            __builtin_amdgcn_s_setprio(0);                                     \
            f32x4 mx4 = vmax4(vmax4(accS[0], accS[1]), vmax4(accS[2], accS[3]));\
            float rmax = fmaxf(fmaxf(mx4[0], mx4[1]), fmaxf(mx4[2], mx4[3]));  \
            if (!__all(fmaf(rmax, C1_, -m2) <= 8.f)) {                         \
                float mx = fmaxf(rmax, __shfl_xor(rmax, 16));                  \
                mx = fmaxf(mx, __shfl_xor(mx, 32));                            \
                float mn = fmaxf(m2, mx * C1_);                                \
                float al = exp2f(m2 - mn);                                     \
                m2 = mn;                                                       \
                _Pragma("unroll")                                              \
                for (int j = 0; j < 4; ++j) lrv[j] *= al;                      \
                _Pragma("unroll")                                              \
                for (int j = 0; j < 4; ++j) {                                  \
                    float aj = __shfl(al, 4 * g + j);                          \
                    _Pragma("unroll")                                          \
                    for (int nt = 0; nt < 4; ++nt) accO[nt][j] *= aj;          \
                }                                                              \
            }                                                                  \
            _Pragma("unroll")                                                  \
            for (int ks = 0; ks < 4; ++ks) {                                   \
                f32x4 e;                                                       \
                _Pragma("unroll")                                              \
                for (int j = 0; j < 4; ++j)                                    \
                    e[j] = exp2f(fmaf(accS[ks][j], C1_, -m2));                 \
                lrv += e;                                                      \
                f16x4v w;                                                      \
                w[0] = (f16)e[0]; w[1] = (f16)e[1];                            \
                w[2] = (f16)e[2]; w[3] = (f16)e[3];                            \
                *(f16x4v*)&Pl[wv][c * 64 + ((16 * ks + 4 * g) ^ swz)] = w;     \
            }                                                                  \
            __builtin_amdgcn_s_setprio(1);                                     \
            _Pragma("unroll")                                                  \
            for (int kh = 0; kh < 2; ++kh) {                                   \
                f16x8 pa = *(const f16x8*)&Pl[wv][c * 64                       \
                                + (((st * 64 + 32 * kh + 8 * g) & 63) ^ swz)]; \
                _Pragma("unroll")                                              \
                for (int nt = 0; nt < 4; ++nt) {                               \
                    f16x8 vb = *(const f16x8*)&Vl[CUR][st][(nt * 16 + c) * 64  \
                                    + ((32 * kh + 8 * g) ^ swz)];              \
                    accO[nt] = mfma16(pa, vb, accO[nt]);                       \
                }                                                              \
            }                                                                  \
            __builtin_amdgcn_s_setprio(0);                                     \
        }                                                                      \
        if (STAGE) {                                                           \
            int nb = (CUR) ^ 1;                                                \
            *(f16x8*)&Kl[nb][kd0] = kreg0; *(f16x8*)&Kl[nb][kd1] = kreg1;      \
            *(f16x8*)&Vl[nb][vst0][vd0] = vreg0;                               \
            *(f16x8*)&Vl[nb][vst1][vd1] = vreg1;                               \
            __syncthreads();                                                   \
        }                                                                      \
    } while (0)

#pragma unroll 1
    for (int kt = 0; kt < 14; kt += 2) {
        ATTN_STEP(0, kt, 1);
        ATTN_STEP(1, kt + 1, 1);
    }
    ATTN_STEP(0, 14, 1);
    ATTN_STEP(1, 15, 0);
#undef ATTN_STEP

    // epilogue: reduce l across g, divide, write ctx
    float lr = (lrv[0] + lrv[1]) + (lrv[2] + lrv[3]);
    lr += __shfl_xor(lr, 16);
    lr += __shfl_xor(lr, 32);
    float inv = 1.f / lr;
#pragma unroll
    for (int j = 0; j < 4; ++j) {
        float lj = __shfl(inv, 4 * g + j);
        int s = qbase + 4 * g + j;
#pragma unroll
        for (int nt = 0; nt < 4; ++nt)
            ctx[((size_t)b * S_ + s) * E_ + h * DH_ + nt * 16 + c] =
                (f16)(accO[nt][j] * lj);
    }
}

// ---------------------------------------------------------------------------
// Kernel 4: out = ctx @ Wo^T + bo. 128x64 tiles, BK=64, swizzled LDS,
// compile-time double-buffer, f16 B (pre-converted Wo), XCD-swizzled 1D grid
// (each XCD owns 2 nbase columns -> Wo slice L2-resident).
// ---------------------------------------------------------------------------
__global__ __launch_bounds__(256) void gemm_out(
    const f16* __restrict__ A,    // ctx [4096][1024] f16
    const f16* __restrict__ Bw,   // Wo f16 [1024][1024]
    const float* __restrict__ bo,
    float* __restrict__ out)      // [4096][1024] fp32
{
    __shared__ __align__(16) f16 Al[2][128 * 64];
    __shared__ __align__(16) f16 Bl[2][64 * 64];

    int tid = threadIdx.x, lane = tid & 63, wv = tid >> 6;
    int bid = blockIdx.x;
    int sb = (bid & 7) * 64 + (bid >> 3);   // XCD-contiguous: nbase-major
    int mbase = (sb & 31) * 128, nbase = (sb >> 5) * 64;
    int c = lane & 15, g = lane >> 4;
    int wr = wv >> 1, wc = wv & 1;
    int swz = (c & 7) << 3;

    int adst[4]; const f16* asrc[4];
#pragma unroll
    for (int i = 0; i < 4; ++i) {
        int slot = tid + i * 256;
        int row = slot >> 3, cc = slot & 7;
        adst[i] = row * 64 + ((cc * 8) ^ ((row & 7) << 3));
        asrc[i] = A + (size_t)(mbase + row) * 1024 + cc * 8;
    }
    int bdst[2]; const f16* bsrc[2];
#pragma unroll
    for (int i = 0; i < 2; ++i) {
        int slot = tid + i * 256;
        int row = slot >> 3, cc = slot & 7;
        bdst[i] = row * 64 + ((cc * 8) ^ ((row & 7) << 3));
        bsrc[i] = Bw + (size_t)(nbase + row) * 1024 + cc * 8;
    }

    f32x4 acc[4][2] = {};
    f16x8 areg[4], breg[2];

    // prologue: stage K-step 0
#pragma unroll
    for (int i = 0; i < 4; ++i) areg[i] = *(const f16x8*)asrc[i];
#pragma unroll
    for (int i = 0; i < 2; ++i) breg[i] = *(const f16x8*)bsrc[i];
#pragma unroll
    for (int i = 0; i < 4; ++i) *(f16x8*)&Al[0][adst[i]] = areg[i];
#pragma unroll
    for (int i = 0; i < 2; ++i) *(f16x8*)&Bl[0][bdst[i]] = breg[i];
    __syncthreads();

#define GEMM_STEP(CUR, T, STAGE)                                               \
    do {                                                                       \
        if (STAGE) {                                                           \
            _Pragma("unroll")                                                  \
            for (int i = 0; i < 4; ++i)                                        \
                areg[i] = *(const f16x8*)(asrc[i] + ((T) + 1) * 64);           \
            _Pragma("unroll")                                                  \
            for (int i = 0; i < 2; ++i)                                        \
                breg[i] = *(const f16x8*)(bsrc[i] + ((T) + 1) * 64);           \
        }                                                                      \
        __builtin_amdgcn_s_setprio(1);                                         \
        _Pragma("unroll")                                                      \
        for (int kk = 0; kk < 2; ++kk) {                                       \
            f16x8 af[4], bf[2];                                                \
            _Pragma("unroll")                                                  \
            for (int mi = 0; mi < 4; ++mi)                                     \
                af[mi] = *(const f16x8*)&Al[CUR][(wr * 64 + mi * 16 + c) * 64  \
                                               + ((32 * kk + 8 * g) ^ swz)];   \
            _Pragma("unroll")                                                  \
            for (int ni = 0; ni < 2; ++ni)                                     \
                bf[ni] = *(const f16x8*)&Bl[CUR][(wc * 32 + ni * 16 + c) * 64  \
                                               + ((32 * kk + 8 * g) ^ swz)];   \
            _Pragma("unroll")                                                  \
            for (int mi = 0; mi < 4; ++mi)                                     \
                _Pragma("unroll")                                              \
                for (int ni = 0; ni < 2; ++ni)                                 \
                    acc[mi][ni] = mfma16(af[mi], bf[ni], acc[mi][ni]);         \
        }                                                                      \
        __builtin_amdgcn_s_setprio(0);                                         \
        if (STAGE) {                                                           \
            int nb = (CUR) ^ 1;                                                \
            _Pragma("unroll")                                                  \
            for (int i = 0; i < 4; ++i) *(f16x8*)&Al[nb][adst[i]] = areg[i];   \
            _Pragma("unroll")                                                  \
            for (int i = 0; i < 2; ++i) *(f16x8*)&Bl[nb][bdst[i]] = breg[i];   \
            __syncthreads();                                                   \
        }                                                                      \
    } while (0)

#pragma unroll 1
    for (int ks = 0; ks < 14; ks += 2) {
        GEMM_STEP(0, ks, 1);
        GEMM_STEP(1, ks + 1, 1);
    }
    GEMM_STEP(0, 14, 1);
    GEMM_STEP(1, 15, 0);
#undef GEMM_STEP

    // epilogue: + bias, fp32 store
#pragma unroll
    for (int ni = 0; ni < 2; ++ni) {
        float bias = bo[nbase + wc * 32 + ni * 16 + c];
#pragma unroll
        for (int mi = 0; mi < 4; ++mi)
#pragma unroll
            for (int j = 0; j < 4; ++j) {
                int m = mbase + wr * 64 + mi * 16 + g * 4 + j;
                out[(size_t)m * 1024 + nbase + wc * 32 + ni * 16 + c] =
                    acc[mi][ni][j] + bias;
            }
    }
}

extern "C" void kernel_launch(void* const* d_in, const int* in_sizes, int n_in,
                              void* d_out, int out_size, void* d_ws, size_t ws_size,
                              hipStream_t stream)
{
    const float* k_in = (const float*)d_in[0];
    const float* q_in = (const float*)d_in[1];
    const float* v_in = (const float*)d_in[2];
    const float* Wq   = (const float*)d_in[3];
    const float* Wk   = (const float*)d_in[4];
    const float* Wv   = (const float*)d_in[5];
    const float* Wo   = (const float*)d_in[6];
    const float* bo   = (const float*)d_in[7];
    float* out = (float*)d_out;

    char* ws = (char*)d_ws;
    f16* Qg  = (f16*)(ws);
    f16* Kg  = (f16*)(ws + (8u << 20));
    f16* Vt  = (f16*)(ws + (16u << 20));
    f16* ctx = (f16*)(ws + (24u << 20));
    f16* WoH = (f16*)(ws + (32u << 20));

    proj_kernel<<<dim3(3072), dim3(256), 0, stream>>>(q_in, k_in, v_in,
                                                      Wq, Wk, Wv, Qg, Kg, Vt);
    cvt_wo<<<dim3(1024), dim3(256), 0, stream>>>(Wo, WoH);
    attn_kernel<<<dim3(512), dim3(512), 0, stream>>>(Qg, Kg, Vt, ctx);
    gemm_out<<<dim3(512), dim3(256), 0, stream>>>(ctx, WoH, bo, out);
}